// Round 6
// baseline (78.493 us; speedup 1.0000x reference)
//
#include <hip/hip_runtime.h>
#include <hip/hip_bf16.h>

typedef __attribute__((ext_vector_type(8))) short short8;
typedef __attribute__((ext_vector_type(4))) float f32x4;

#define TEMP_INV 20.0f
#define NCH 1024

__device__ inline unsigned short f2bf(float f){
    unsigned int u = __builtin_bit_cast(unsigned int, f);
    u += 0x7fffu + ((u >> 16) & 1u);
    return (unsigned short)(u >> 16);
}
__device__ inline float bf2f(unsigned short h){
    unsigned int u = ((unsigned int)h) << 16;
    return __builtin_bit_cast(float, u);
}
__device__ inline unsigned int pk2bf(float a, float b){
    return (unsigned int)f2bf(a) | ((unsigned int)f2bf(b) << 16);
}

#define GLOAD16(src, dst) __builtin_amdgcn_global_load_lds( \
    (const __attribute__((address_space(1))) unsigned int*)(src), \
    (__attribute__((address_space(3))) unsigned int*)(dst), 16, 0, 0)

// ---------------------------------------------------------------------------
// k_norm: normalize query rows -> bf16 A, pre-swizzled per-64-col K-chunk
// tiles [12][256][64] so k_main can global_load_lds linearly. Zeroes out[0].
// ---------------------------------------------------------------------------
__global__ __launch_bounds__(256) void k_norm(const float* __restrict__ q,
                                              unsigned short* __restrict__ Aswz,
                                              float* __restrict__ out){
    int b = blockIdx.x, t = threadIdx.x;
    if (b == 0 && t == 0) out[0] = 0.f;
    const float* qr = q + b * 768;
    float v0 = qr[t], v1 = qr[t + 256], v2 = qr[t + 512];
    float ss = v0*v0 + v1*v1 + v2*v2;
#pragma unroll
    for (int o = 32; o; o >>= 1) ss += __shfl_xor(ss, o);
    __shared__ float red[4];
    if ((t & 63) == 0) red[t >> 6] = ss;
    __syncthreads();
    ss = red[0] + red[1] + red[2] + red[3];
    float inv = 1.0f / fmaxf(sqrtf(ss), 1e-8f);
    float nv[3] = {v0 * inv, v1 * inv, v2 * inv};
#pragma unroll
    for (int j = 0; j < 3; j++){
        int cc = t + 256 * j;
        unsigned short h = f2bf(nv[j]);
        int kc = cc >> 6, kl = cc & 63, g = kl >> 3, e = kl & 7;
        int slot = g ^ (b & 7);
        Aswz[kc * 16384 + b * 64 + slot * 8 + e] = h;
    }
}

// ---------------------------------------------------------------------------
// k_main: 1024 blocks x 512 threads (8 waves) -> 2 blocks/CU resident
// (__launch_bounds__(512,4): 4 waves/EU = 16 waves/CU). Block b owns queue
// rows [64b, 64b+64) as a 256x64 MFMA tile (on-the-fly B row-norm);
// blocks b<256 additionally compute key column b via a distributed bf16
// dot (gives sim_pos and diag). Simple m97-style 2-barrier K-loop; the
// sibling block on each CU hides barrier/drain stalls (m114 overlap).
// ---------------------------------------------------------------------------
__global__ __launch_bounds__(512, 4) void k_main(
        const float* __restrict__ keys,
        const float* __restrict__ queue,
        const unsigned short* __restrict__ Aswz,
        float* __restrict__ pmax,
        float* __restrict__ psum,
        float* __restrict__ diag){
    __shared__ unsigned short Atile[16384];  // 32 KB [256][64] swizzled
    __shared__ unsigned short Btile[4096];   //  8 KB [64][64]  swizzled
    __shared__ unsigned short bxn16[768];    //  1.5 KB normalized key (bf16)
    __shared__ float invn[64];
    __shared__ float redm[2][256];
    __shared__ float reds[2][256];
    __shared__ float xred[2][256];
    __shared__ float wred[8];
    __shared__ float sxs;

    const int b = blockIdx.x, t = threadIdx.x;
    const int lane = t & 63;
    const int w = t >> 6;                 // 0..7
    const int wm = w >> 1, wn = w & 1;    // 4m x 2n waves, each 64x32
    const int frow = lane & 15, fg = lane >> 4;
    const int r = t >> 3, q8 = t & 7;     // B staging: 8 threads/row
    const bool keyblk = (b < 256);

    // ----- prologue (key blocks): normalize key row b into bxn16 -----
    if (keyblk){
        const float* krow = keys + b * 768;
        float v0 = krow[t];
        float v1 = (t < 256) ? krow[512 + t] : 0.f;
        float ssx = v0 * v0 + v1 * v1;
#pragma unroll
        for (int o = 32; o; o >>= 1) ssx += __shfl_xor(ssx, o);
        if (lane == 0) wred[w] = ssx;
        __syncthreads();
        if (t == 0){
            float s = 0.f;
#pragma unroll
            for (int i = 0; i < 8; i++) s += wred[i];
            sxs = 1.0f / fmaxf(sqrtf(s), 1e-8f);
        }
        __syncthreads();
        bxn16[t] = f2bf(v0 * sxs);
        if (t < 256) bxn16[512 + t] = f2bf(v1 * sxs);
        __syncthreads();
    }

    const float* rp = queue + (size_t)(b * 64 + r) * 768 + q8 * 4;
    const int xrow = t & 255, xk = t >> 8;  // key-dot: 2 k-slices x 256 rows

    float ssq = 0.f, dx = 0.f;
    f32x4 acc[4][2];
#pragma unroll
    for (int i = 0; i < 4; i++)
#pragma unroll
        for (int j = 0; j < 2; j++) acc[i][j] = (f32x4)0.f;

    for (int kc = 0; kc < 12; ++kc){
        if (kc) __syncthreads();
        // stage A(kc): 4 x 16B per thread, linear (pre-swizzled in ws)
#pragma unroll
        for (int i = 0; i < 4; i++)
            GLOAD16(Aswz + kc * 16384 + i * 4096 + t * 8,
                    Atile + i * 4096 + t * 8);
        // stage B(kc): load f32, ssq, convert, swizzled ds_write
        float4 u0 = *(const float4*)(rp + kc * 64);
        float4 u1 = *(const float4*)(rp + kc * 64 + 32);
        ssq += u0.x*u0.x + u0.y*u0.y + u0.z*u0.z + u0.w*u0.w;
        ssq += u1.x*u1.x + u1.y*u1.y + u1.z*u1.z + u1.w*u1.w;
        {
            int slot0 = (q8 >> 1) ^ (r & 7);
            int slot1 = ((q8 + 8) >> 1) ^ (r & 7);
            uint2 pk0, pk1;
            pk0.x = pk2bf(u0.x, u0.y); pk0.y = pk2bf(u0.z, u0.w);
            pk1.x = pk2bf(u1.x, u1.y); pk1.y = pk2bf(u1.z, u1.w);
            *(uint2*)&Btile[r * 64 + slot0 * 8 + (q8 & 1) * 4] = pk0;
            *(uint2*)&Btile[r * 64 + slot1 * 8 + (q8 & 1) * 4] = pk1;
        }
        __syncthreads();   // compiler drains vmcnt+lgkmcnt here (gloads done)

        // MFMA over this K-chunk
#pragma unroll
        for (int ks = 0; ks < 2; ++ks){
            short8 af[4], bfv[2];
#pragma unroll
            for (int fm = 0; fm < 4; ++fm){
                int row = wm * 64 + fm * 16 + frow;
                int slot = (ks * 4 + fg) ^ (frow & 7);
                af[fm] = *(const short8*)&Atile[row * 64 + slot * 8];
            }
#pragma unroll
            for (int fn = 0; fn < 2; ++fn){
                int row = wn * 32 + fn * 16 + frow;
                int slot = (ks * 4 + fg) ^ (frow & 7);
                bfv[fn] = *(const short8*)&Btile[row * 64 + slot * 8];
            }
#pragma unroll
            for (int fm = 0; fm < 4; ++fm)
#pragma unroll
                for (int fn = 0; fn < 2; ++fn)
                    acc[fm][fn] = __builtin_amdgcn_mfma_f32_16x16x32_bf16(
                        af[fm], bfv[fn], acc[fm][fn], 0, 0, 0);
        }

        // key-column dot partials (key blocks only)
        if (keyblk){
#pragma unroll
            for (int gi = 0; gi < 4; ++gi){
                int g = xk * 4 + gi;
                short8 av = *(const short8*)&Atile[xrow * 64 + (g ^ (xrow & 7)) * 8];
                short8 xv = *(const short8*)&bxn16[kc * 64 + g * 8];
#pragma unroll
                for (int e = 0; e < 8; ++e)
                    dx += bf2f((unsigned short)av[e]) * bf2f((unsigned short)xv[e]);
            }
        }
    }

    // ---- epilogue: B-col norms, scale, per-row online-softmax partials ----
    ssq += __shfl_xor(ssq, 1);
    ssq += __shfl_xor(ssq, 2);
    ssq += __shfl_xor(ssq, 4);
    if (q8 == 0) invn[r] = 1.0f / fmaxf(sqrtf(ssq), 1e-8f);
    if (keyblk) xred[xk][xrow] = dx;
    __syncthreads();

#pragma unroll
    for (int fm = 0; fm < 4; ++fm){
#pragma unroll
        for (int rr = 0; rr < 4; ++rr){
            float v0 = acc[fm][0][rr] * invn[wn * 32 + frow] * TEMP_INV;
            float v1 = acc[fm][1][rr] * invn[wn * 32 + 16 + frow] * TEMP_INV;
            int row = wm * 64 + fm * 16 + fg * 4 + rr;
            float m = fmaxf(v0, v1);
#pragma unroll
            for (int o = 1; o < 16; o <<= 1) m = fmaxf(m, __shfl_xor(m, o));
            float s = __expf(v0 - m) + __expf(v1 - m);
#pragma unroll
            for (int o = 1; o < 16; o <<= 1) s += __shfl_xor(s, o);
            if (frow == 0){ redm[wn][row] = m; reds[wn][row] = s; }
        }
    }
    __syncthreads();
    if (t < 256){
        float m0 = redm[0][t], m1 = redm[1][t];
        float M = fmaxf(m0, m1);
        float S = reds[0][t] * __expf(m0 - M) + reds[1][t] * __expf(m1 - M);
        if (keyblk){
            float vx = (xred[0][t] + xred[1][t]) * TEMP_INV;
            if (t == b) diag[b] = vx;
            float M2 = fmaxf(M, vx);
            S = S * __expf(M - M2) + __expf(vx - M2);
            M = M2;
        }
        pmax[b * 256 + t] = M;
        psum[b * 256 + t] = S;
    }
}

// ---------------------------------------------------------------------------
// k_lse: per q-row, merge 1024 chunk partials; atomicAdd loss contribution.
// ---------------------------------------------------------------------------
__global__ __launch_bounds__(256) void k_lse(const float* __restrict__ pmax,
                                             const float* __restrict__ psum,
                                             const float* __restrict__ diag,
                                             float* __restrict__ out){
    int b = blockIdx.x, t = threadIdx.x;
    float m = -1e30f;
    for (int cc = t; cc < NCH; cc += 256) m = fmaxf(m, pmax[cc * 256 + b]);
#pragma unroll
    for (int o = 32; o; o >>= 1) m = fmaxf(m, __shfl_xor(m, o));
    __shared__ float red[4];
    __shared__ float Msh;
    if ((t & 63) == 0) red[t >> 6] = m;
    __syncthreads();
    if (t == 0) Msh = fmaxf(fmaxf(red[0], red[1]), fmaxf(red[2], red[3]));
    __syncthreads();
    float M = Msh;
    float s = 0.f;
    for (int cc = t; cc < NCH; cc += 256) s += psum[cc * 256 + b] * __expf(pmax[cc * 256 + b] - M);
#pragma unroll
    for (int o = 32; o; o >>= 1) s += __shfl_xor(s, o);
    if ((t & 63) == 0) red[t >> 6] = s;
    __syncthreads();
    if (t == 0)
        atomicAdd(out, (M + logf(red[0] + red[1] + red[2] + red[3]) - diag[b]) * (1.0f / 256.0f));
}

extern "C" void kernel_launch(void* const* d_in, const int* in_sizes, int n_in,
                              void* d_out, int out_size, void* d_ws, size_t ws_size,
                              hipStream_t stream){
    const float* q  = (const float*)d_in[0];
    const float* k  = (const float*)d_in[1];
    const float* qu = (const float*)d_in[2];
    char* ws = (char*)d_ws;
    // ws layout (bytes): Aswz 0..393216 | diag ..394240 |
    //                    pmax ..1442816 | psum ..2491392
    unsigned short* Aswz = (unsigned short*)(ws);
    float* diag  = (float*)(ws + 393216);
    float* pmax  = (float*)(ws + 394240);
    float* psum  = (float*)(ws + 1442816);

    k_norm<<<256, 256, 0, stream>>>(q, Aswz, (float*)d_out);
    k_main<<<1024, 512, 0, stream>>>(k, qu, Aswz, pmax, psum, diag);
    k_lse<<<256, 256, 0, stream>>>(pmax, psum, diag, (float*)d_out);
}

// Round 8
// 77.869 us; speedup vs baseline: 1.0080x; 1.0080x over previous
//
#include <hip/hip_runtime.h>
#include <hip/hip_bf16.h>

typedef __attribute__((ext_vector_type(8))) short short8;
typedef __attribute__((ext_vector_type(4))) float f32x4;

#define TEMP_INV 20.0f
#define NCH 256

__device__ inline unsigned short f2bf(float f){
    unsigned int u = __builtin_bit_cast(unsigned int, f);
    u += 0x7fffu + ((u >> 16) & 1u);
    return (unsigned short)(u >> 16);
}
__device__ inline float bf2f(unsigned short h){
    unsigned int u = ((unsigned int)h) << 16;
    return __builtin_bit_cast(float, u);
}
__device__ inline unsigned int pk2bf(float a, float b){
    return (unsigned int)f2bf(a) | ((unsigned int)f2bf(b) << 16);
}

#define GLOAD16(src, dst) __builtin_amdgcn_global_load_lds( \
    (const __attribute__((address_space(1))) unsigned int*)(src), \
    (__attribute__((address_space(3))) unsigned int*)(dst), 16, 0, 0)

// ---------------------------------------------------------------------------
// k_norm: normalize query rows -> bf16 A, pre-swizzled per-64-col K-chunk
// tiles [12][256][64] so k_main can global_load_lds linearly. Zeroes out[0].
// ---------------------------------------------------------------------------
__global__ __launch_bounds__(256) void k_norm(const float* __restrict__ q,
                                              unsigned short* __restrict__ Aswz,
                                              float* __restrict__ out){
    int b = blockIdx.x, t = threadIdx.x;
    if (b == 0 && t == 0) out[0] = 0.f;
    const float* qr = q + b * 768;
    float v0 = qr[t], v1 = qr[t + 256], v2 = qr[t + 512];
    float ss = v0*v0 + v1*v1 + v2*v2;
#pragma unroll
    for (int o = 32; o; o >>= 1) ss += __shfl_xor(ss, o);
    __shared__ float red[4];
    if ((t & 63) == 0) red[t >> 6] = ss;
    __syncthreads();
    ss = red[0] + red[1] + red[2] + red[3];
    float inv = 1.0f / fmaxf(sqrtf(ss), 1e-8f);
    float nv[3] = {v0 * inv, v1 * inv, v2 * inv};
#pragma unroll
    for (int j = 0; j < 3; j++){
        int cc = t + 256 * j;
        unsigned short h = f2bf(nv[j]);
        int kc = cc >> 6, kl = cc & 63, g = kl >> 3, e = kl & 7;
        int slot = g ^ (b & 7);
        Aswz[kc * 16384 + b * 64 + slot * 8 + e] = h;
    }
}

// ---------------------------------------------------------------------------
// k_main: 256 blocks x 1024 threads (16 waves, 1 block/CU). Block b owns
// queue cols [256b, 256b+256) as ONE 256x256 MFMA tile (single pass,
// 4m x 4n waves of 64x64, acc[4][4]) + key column b via distributed bf16
// dot (gives sim_pos chunk partials and diag). m97-style 2-barrier K-loop.
// Geometry minimizes LDS fragment traffic: A-read = 4x384KB (was 8x in R4).
// ---------------------------------------------------------------------------
__global__ __launch_bounds__(1024) void k_main(
        const float* __restrict__ keys,
        const float* __restrict__ queue,
        const unsigned short* __restrict__ Aswz,
        float* __restrict__ pmax,
        float* __restrict__ psum,
        float* __restrict__ diag){
    __shared__ unsigned short Atile[16384];  // 32 KB [256][64] swizzled
    __shared__ unsigned short Btile[16384];  // 32 KB [256][64] swizzled
    __shared__ unsigned short bxn16[768];    // normalized key b (bf16)
    __shared__ float invn[256];
    __shared__ float redm[4][256];
    __shared__ float reds[4][256];
    __shared__ float xred[4][256];
    __shared__ float wred[16];
    __shared__ float sxs;

    const int b = blockIdx.x, t = threadIdx.x;
    const int lane = t & 63;
    const int w = t >> 6;                 // 0..15
    const int wm = w >> 2, wn = w & 3;    // 4m x 4n waves, each 64x64
    const int frow = lane & 15, fg = lane >> 4;
    const int c = t >> 2, q4 = t & 3;     // B staging: 4 threads/col, 16 elems
    const int c7 = c & 7;

    // ----- prologue: normalize key row b into bxn16 -----
    {
        float v = (t < 768) ? keys[b * 768 + t] : 0.f;
        float ssx = v * v;
#pragma unroll
        for (int o = 32; o; o >>= 1) ssx += __shfl_xor(ssx, o);
        if (lane == 0) wred[w] = ssx;
        __syncthreads();
        if (t == 0){
            float s = 0.f;
#pragma unroll
            for (int i = 0; i < 16; i++) s += wred[i];
            sxs = 1.0f / fmaxf(sqrtf(s), 1e-8f);
        }
        __syncthreads();
        if (t < 768) bxn16[t] = f2bf(v * sxs);
        __syncthreads();
    }

    const float* rp = queue + (size_t)(b * 256 + c) * 768 + q4 * 16;
    const int xrow = t & 255, xk = t >> 8;  // key-dot: 4 k-slices x 256 rows

    float ssq = 0.f, dx = 0.f;
    f32x4 acc[4][4];
#pragma unroll
    for (int i = 0; i < 4; i++)
#pragma unroll
        for (int j = 0; j < 4; j++) acc[i][j] = (f32x4)0.f;

    for (int kc = 0; kc < 12; ++kc){
        if (kc) __syncthreads();
        // stage A(kc): 2 x 16B per thread, linear (pre-swizzled in ws)
        GLOAD16(Aswz + kc * 16384 + t * 8, Atile + t * 8);
        GLOAD16(Aswz + kc * 16384 + 8192 + t * 8, Atile + 8192 + t * 8);
        // stage B(kc): 16 f32 per thread -> ssq -> bf16 -> 2 swizzled b128
        {
            float4 u0 = *(const float4*)(rp + kc * 64);
            float4 u1 = *(const float4*)(rp + kc * 64 + 4);
            float4 u2 = *(const float4*)(rp + kc * 64 + 8);
            float4 u3 = *(const float4*)(rp + kc * 64 + 12);
            ssq += u0.x*u0.x + u0.y*u0.y + u0.z*u0.z + u0.w*u0.w;
            ssq += u1.x*u1.x + u1.y*u1.y + u1.z*u1.z + u1.w*u1.w;
            ssq += u2.x*u2.x + u2.y*u2.y + u2.z*u2.z + u2.w*u2.w;
            ssq += u3.x*u3.x + u3.y*u3.y + u3.z*u3.z + u3.w*u3.w;
            uint4 pk0, pk1;
            pk0.x = pk2bf(u0.x, u0.y); pk0.y = pk2bf(u0.z, u0.w);
            pk0.z = pk2bf(u1.x, u1.y); pk0.w = pk2bf(u1.z, u1.w);
            pk1.x = pk2bf(u2.x, u2.y); pk1.y = pk2bf(u2.z, u2.w);
            pk1.z = pk2bf(u3.x, u3.y); pk1.w = pk2bf(u3.z, u3.w);
            int slot0 = (q4 * 2) ^ c7;
            int slot1 = (q4 * 2 + 1) ^ c7;
            *(uint4*)&Btile[c * 64 + slot0 * 8] = pk0;
            *(uint4*)&Btile[c * 64 + slot1 * 8] = pk1;
        }
        __syncthreads();   // compiler drains vmcnt+lgkmcnt (A landed, B written)

        // MFMA over this K-chunk: 2 ks x 4 fm x 4 fn
#pragma unroll
        for (int ks = 0; ks < 2; ++ks){
            const int slotv = (ks * 4 + fg) ^ (frow & 7);
            short8 af[4], bfv[4];
#pragma unroll
            for (int fm = 0; fm < 4; ++fm)
                af[fm] = *(const short8*)&Atile[(wm * 64 + fm * 16 + frow) * 64 + slotv * 8];
#pragma unroll
            for (int fn = 0; fn < 4; ++fn)
                bfv[fn] = *(const short8*)&Btile[(wn * 64 + fn * 16 + frow) * 64 + slotv * 8];
#pragma unroll
            for (int fm = 0; fm < 4; ++fm)
#pragma unroll
                for (int fn = 0; fn < 4; ++fn)
                    acc[fm][fn] = __builtin_amdgcn_mfma_f32_16x16x32_bf16(
                        af[fm], bfv[fn], acc[fm][fn], 0, 0, 0);
        }

        // key-column dot partials: 4 k-slices x 256 rows, 16 elems each
#pragma unroll
        for (int gi = 0; gi < 2; ++gi){
            int g = xk * 2 + gi;
            short8 av = *(const short8*)&Atile[xrow * 64 + (g ^ (xrow & 7)) * 8];
            short8 xv = *(const short8*)&bxn16[kc * 64 + g * 8];
#pragma unroll
            for (int e = 0; e < 8; ++e)
                dx += bf2f((unsigned short)av[e]) * bf2f((unsigned short)xv[e]);
        }
    }

    // ---- epilogue: B-col norms, scale, per-row online-softmax partials ----
    ssq += __shfl_xor(ssq, 1);
    ssq += __shfl_xor(ssq, 2);
    if (q4 == 0) invn[c] = 1.0f / fmaxf(sqrtf(ssq), 1e-8f);
    xred[xk][xrow] = dx;
    __syncthreads();

#pragma unroll
    for (int fm = 0; fm < 4; ++fm){
#pragma unroll
        for (int rr = 0; rr < 4; ++rr){
            float v[4];
#pragma unroll
            for (int fn = 0; fn < 4; ++fn)
                v[fn] = acc[fm][fn][rr] * invn[wn * 64 + fn * 16 + frow] * TEMP_INV;
            int row = wm * 64 + fm * 16 + fg * 4 + rr;
            float m = fmaxf(fmaxf(v[0], v[1]), fmaxf(v[2], v[3]));
#pragma unroll
            for (int o = 1; o < 16; o <<= 1) m = fmaxf(m, __shfl_xor(m, o));
            float s = __expf(v[0]-m) + __expf(v[1]-m) + __expf(v[2]-m) + __expf(v[3]-m);
#pragma unroll
            for (int o = 1; o < 16; o <<= 1) s += __shfl_xor(s, o);
            if (frow == 0){ redm[wn][row] = m; reds[wn][row] = s; }
        }
    }
    __syncthreads();
    if (t < 256){
        float M = -1e30f, S = 0.f;
#pragma unroll
        for (int ww = 0; ww < 4; ++ww){
            float m2 = redm[ww][t], s2 = reds[ww][t];
            float Mn = fmaxf(M, m2);
            S = S * __expf(M - Mn) + s2 * __expf(m2 - Mn);
            M = Mn;
        }
        // merge key column b
        float vx = (xred[0][t] + xred[1][t] + xred[2][t] + xred[3][t]) * TEMP_INV;
        if (t == b) diag[b] = vx;
        float Mn = fmaxf(M, vx);
        S = S * __expf(M - Mn) + __expf(vx - Mn);
        pmax[b * 256 + t] = Mn;
        psum[b * 256 + t] = S;
    }
}

// ---------------------------------------------------------------------------
// k_lse: per q-row, merge 256 chunk partials; atomicAdd loss contribution.
// ---------------------------------------------------------------------------
__global__ __launch_bounds__(256) void k_lse(const float* __restrict__ pmax,
                                             const float* __restrict__ psum,
                                             const float* __restrict__ diag,
                                             float* __restrict__ out){
    int b = blockIdx.x, t = threadIdx.x;
    float m = -1e30f;
    for (int cc = t; cc < NCH; cc += 256) m = fmaxf(m, pmax[cc * 256 + b]);
#pragma unroll
    for (int o = 32; o; o >>= 1) m = fmaxf(m, __shfl_xor(m, o));
    __shared__ float red[4];
    __shared__ float Msh;
    if ((t & 63) == 0) red[t >> 6] = m;
    __syncthreads();
    if (t == 0) Msh = fmaxf(fmaxf(red[0], red[1]), fmaxf(red[2], red[3]));
    __syncthreads();
    float M = Msh;
    float s = 0.f;
    for (int cc = t; cc < NCH; cc += 256) s += psum[cc * 256 + b] * __expf(pmax[cc * 256 + b] - M);
#pragma unroll
    for (int o = 32; o; o >>= 1) s += __shfl_xor(s, o);
    if ((t & 63) == 0) red[t >> 6] = s;
    __syncthreads();
    if (t == 0)
        atomicAdd(out, (M + logf(red[0] + red[1] + red[2] + red[3]) - diag[b]) * (1.0f / 256.0f));
}

extern "C" void kernel_launch(void* const* d_in, const int* in_sizes, int n_in,
                              void* d_out, int out_size, void* d_ws, size_t ws_size,
                              hipStream_t stream){
    const float* q  = (const float*)d_in[0];
    const float* k  = (const float*)d_in[1];
    const float* qu = (const float*)d_in[2];
    char* ws = (char*)d_ws;
    // ws layout (bytes): Aswz 0..393216 | diag ..394240 | pmax ..656384
    //                    psum ..918528
    unsigned short* Aswz = (unsigned short*)(ws);
    float* diag  = (float*)(ws + 393216);
    float* pmax  = (float*)(ws + 394240);
    float* psum  = (float*)(ws + 656384);

    k_norm<<<256, 256, 0, stream>>>(q, Aswz, (float*)d_out);
    k_main<<<256, 1024, 0, stream>>>(k, qu, Aswz, pmax, psum, diag);
    k_lse<<<256, 256, 0, stream>>>(pmax, psum, diag, (float*)d_out);
}